// Round 1
// baseline (1790.637 us; speedup 1.0000x reference)
//
#include <hip/hip_runtime.h>
#include <hip/hip_bf16.h>

// ---- problem constants ----
#define B_   16384
#define H_   128
#define C_   4
#define L_   6
#define O_   1024
#define G3H  384
#define CB   (C_ * B_)
#define CBH  (C_ * B_ * H_)

typedef __hip_bfloat16 bf16;
using bf16x8  = __attribute__((ext_vector_type(8))) __bf16;
using floatx4 = __attribute__((ext_vector_type(4))) float;

__device__ __forceinline__ bf16 f2bf(float x) { return __float2bfloat16(x); }
__device__ __forceinline__ float bf2f(bf16 x) { return __bfloat162float(x); }
__device__ __forceinline__ void store_val(float* p, float v) { *p = v; }
__device__ __forceinline__ void store_val(bf16* p, float v) { *p = f2bf(v); }

__device__ __forceinline__ floatx4 mfma16(bf16x8 a, bf16x8 b, floatx4 c) {
  return __builtin_amdgcn_mfma_f32_16x16x32_bf16(a, b, c, 0, 0, 0);
}

// fragment loaders: 8 consecutive K elements
__device__ __forceinline__ bf16x8 load8(const bf16* p) { return *(const bf16x8*)p; }
__device__ __forceinline__ bf16x8 load8(const float* p) {
  const float4 a = *(const float4*)p;
  const float4 b = *(const float4*)(p + 4);
  bf16x8 r;
  r[0] = (__bf16)a.x; r[1] = (__bf16)a.y; r[2] = (__bf16)a.z; r[3] = (__bf16)a.w;
  r[4] = (__bf16)b.x; r[5] = (__bf16)b.y; r[6] = (__bf16)b.z; r[7] = (__bf16)b.w;
  return r;
}

__device__ __forceinline__ float wave_sum(float x) {
#pragma unroll
  for (int off = 32; off; off >>= 1) x += __shfl_xor(x, off);
  return x;
}

// f32 -> bf16 conversion (weights, once per launch)
__global__ __launch_bounds__(256) void cvt_kernel(const float* __restrict__ in,
                                                  bf16* __restrict__ out, long n) {
  long i = (long)blockIdx.x * 256 + threadIdx.x;
  if (i < n) out[i] = f2bf(in[i]);
}

// ---------------------------------------------------------------------------
// Generic GEMM (head only now): out[r, n] = sum_k A[r,k] * W[n,k] + bias[n]
// Fragment layouts (m89-verified):
//   A/B frag: m|n = lane&15, k = (lane>>4)*8 + j
//   C/D:      col(n) = lane&15, row(m) = (lane>>4)*4 + reg
// ---------------------------------------------------------------------------
template <typename AT, typename OutT>
__global__ __launch_bounds__(256) void gemm_bt(const AT* __restrict__ A,
                                               const bf16* __restrict__ W,
                                               const float* __restrict__ bias,
                                               OutT* __restrict__ out,
                                               int N, int rows_per_batch,
                                               long wstride, long bstride) {
  const int wave = threadIdx.x >> 6;
  const int lane = threadIdx.x & 63;
  const int m0   = blockIdx.x * 16;
  const int n0   = blockIdx.y * 64 + wave * 16;
  const int sub  = lane & 15;
  const int quad = lane >> 4;
  const int batch = m0 / rows_per_batch;
  const bf16*  Wb = W + (long)batch * wstride;
  const float* Bi = bias + (long)batch * bstride;

  const AT*   Ap = A + (long)(m0 + sub) * 128 + quad * 8;
  const bf16* Wp = Wb + (long)(n0 + sub) * 128 + quad * 8;

  floatx4 acc = {0.f, 0.f, 0.f, 0.f};
#pragma unroll
  for (int kc = 0; kc < 4; ++kc) {
    acc = mfma16(load8(Ap + kc * 32), load8(Wp + kc * 32), acc);
  }

  const int col = n0 + sub;
  const float bv = Bi[col];
#pragma unroll
  for (int r = 0; r < 4; ++r) {
    long row = m0 + quad * 4 + r;
    store_val(&out[row * (long)N + col], acc[r] + bv);
  }
}

// x0[b,:] = bf16(emb[tokens[b],:])
__global__ __launch_bounds__(128) void embed_kernel(const int* __restrict__ tok,
                                                    const float* __restrict__ emb,
                                                    bf16* __restrict__ x0) {
  const int b = blockIdx.x;
  x0[(long)b * 128 + threadIdx.x] = f2bf(emb[(long)tok[b] * 128 + threadIdx.x]);
}

// ---------------------------------------------------------------------------
// Fused per-cell kernel: gi = x@wih^T + bih, gh = h@whh^T + bhh (accumulated
// together for the r/z gate halves), GRU elementwise -> hn (f32 global +
// bf16 LDS), then qkv = hn@ainw^T + ainb -> global bf16.
// One block = 16 rows of (c,b); 4 waves x 6 col-tiles of 16 per GEMM phase.
// L0: layer-0 special case (cell0 A = x0 bf16; cells 1-3 gi = bias only).
// LDS strides padded so stores/loads are <=2-way bank-aliased:
//   szx 268 f32 (268%32=12), gin/ghn 132 (132%32=4), hn_s 152 bf16
//   (304B = 76 dwords, 76%32=12; 16B-aligned for b128 reads).
// ---------------------------------------------------------------------------
template <bool L0>
__global__ __launch_bounds__(256) void cell_fused(const float* __restrict__ x,
                                                  const bf16* __restrict__ x0,
                                                  const bf16* __restrict__ wih_l,
                                                  const float* __restrict__ bih_l,
                                                  const float* __restrict__ h,
                                                  const bf16* __restrict__ whh_l,
                                                  const float* __restrict__ bhh_l,
                                                  const bf16* __restrict__ ainw,
                                                  const float* __restrict__ ainb,
                                                  float* __restrict__ hn,
                                                  bf16* __restrict__ qkv) {
  __shared__ float szx_s[16 * 268];   // sigmoid args: ir+hr (cols 0-127), iz+hz (128-255)
  __shared__ float gin_s[16 * 132];   // i_n
  __shared__ float ghn_s[16 * 132];   // h_n
  __shared__ bf16  hn_s[16 * 152];    // hn in bf16, A-operand for qkv GEMM

  const int wave = threadIdx.x >> 6, lane = threadIdx.x & 63;
  const int sub = lane & 15, quad = lane >> 4;
  const int m0 = blockIdx.x * 16;
  const int cell = m0 / B_;
  const bool has_gi = (!L0) || (cell == 0);

  // A fragments for h (reused across all 6 col tiles)
  const float* Hp = h + (long)(m0 + sub) * H_ + quad * 8;
  bf16x8 h0 = load8(Hp), h1 = load8(Hp + 32), h2 = load8(Hp + 64), h3 = load8(Hp + 96);

  // A fragments for x (hn_prev or x0)
  bf16x8 xa0, xa1, xa2, xa3;
  if (has_gi) {
    if constexpr (L0) {
      const bf16* Xp = x0 + (long)(m0 + sub) * H_ + quad * 8;
      xa0 = load8(Xp); xa1 = load8(Xp + 32); xa2 = load8(Xp + 64); xa3 = load8(Xp + 96);
    } else {
      const float* Xp = x + (long)(m0 + sub) * H_ + quad * 8;
      xa0 = load8(Xp); xa1 = load8(Xp + 32); xa2 = load8(Xp + 64); xa3 = load8(Xp + 96);
    }
  }

  const bf16*  Wh = whh_l + (long)cell * G3H * H_;
  const bf16*  Wi = L0 ? wih_l : wih_l + (long)cell * G3H * H_;
  const float* bh = bhh_l + cell * G3H;
  const float* bi = bih_l + cell * G3H;

#pragma unroll
  for (int t = 0; t < 6; ++t) {
    const int n0 = wave * 96 + t * 16;
    const int col = n0 + sub;
    const bf16* Whp = Wh + (long)col * H_ + quad * 8;
    floatx4 acch = {0.f, 0.f, 0.f, 0.f};
    acch = mfma16(h0, load8(Whp), acch);
    acch = mfma16(h1, load8(Whp + 32), acch);
    acch = mfma16(h2, load8(Whp + 64), acch);
    acch = mfma16(h3, load8(Whp + 96), acch);
    floatx4 acci = {0.f, 0.f, 0.f, 0.f};
    if (has_gi) {
      const bf16* Wip = Wi + (long)col * H_ + quad * 8;
      acci = mfma16(xa0, load8(Wip), acci);
      acci = mfma16(xa1, load8(Wip + 32), acci);
      acci = mfma16(xa2, load8(Wip + 64), acci);
      acci = mfma16(xa3, load8(Wip + 96), acci);
    }
    const float bhv = bh[col], biv = bi[col];
    if (n0 < 256) {  // r,z halves: gi+gh summed
#pragma unroll
      for (int r = 0; r < 4; ++r)
        szx_s[(quad * 4 + r) * 268 + col] = acch[r] + acci[r] + bhv + biv;
    } else {         // n parts stay separate
#pragma unroll
      for (int r = 0; r < 4; ++r) {
        ghn_s[(quad * 4 + r) * 132 + col - 256] = acch[r] + bhv;
        gin_s[(quad * 4 + r) * 132 + col - 256] = acci[r] + biv;
      }
    }
  }
  __syncthreads();

  // GRU elementwise: thread -> (row = tid>>4, 8 consecutive cols)
  const int row = threadIdx.x >> 4;
  const int cb = (threadIdx.x & 15) * 8;
  const long grow = m0 + row;
  const float* hr = h + grow * H_;
  float* outr = hn + grow * H_;
  float hv[8];
  {
    const float4 u = *(const float4*)(hr + cb);
    const float4 v = *(const float4*)(hr + cb + 4);
    hv[0] = u.x; hv[1] = u.y; hv[2] = u.z; hv[3] = u.w;
    hv[4] = v.x; hv[5] = v.y; hv[6] = v.z; hv[7] = v.w;
  }
  float ov[8];
#pragma unroll
  for (int j = 0; j < 8; ++j) {
    const int c = cb + j;
    float rg = 1.f / (1.f + __expf(-szx_s[row * 268 + c]));
    float zg = 1.f / (1.f + __expf(-szx_s[row * 268 + 128 + c]));
    float ng = tanhf(gin_s[row * 132 + c] + rg * ghn_s[row * 132 + c]);
    ov[j] = (1.f - zg) * ng + zg * hv[j];
    hn_s[row * 152 + c] = f2bf(ov[j]);
  }
  *(float4*)(outr + cb) = make_float4(ov[0], ov[1], ov[2], ov[3]);
  *(float4*)(outr + cb + 4) = make_float4(ov[4], ov[5], ov[6], ov[7]);
  __syncthreads();

  // qkv GEMM: A = hn_s (bf16 LDS), W = ainw
  const bf16* Anp = hn_s + sub * 152 + quad * 8;
  bf16x8 a0 = load8(Anp), a1 = load8(Anp + 32), a2 = load8(Anp + 64), a3 = load8(Anp + 96);
#pragma unroll
  for (int t = 0; t < 6; ++t) {
    const int n0 = wave * 96 + t * 16;
    const int col = n0 + sub;
    const bf16* Wp = ainw + (long)col * H_ + quad * 8;
    floatx4 acc = {0.f, 0.f, 0.f, 0.f};
    acc = mfma16(a0, load8(Wp), acc);
    acc = mfma16(a1, load8(Wp + 32), acc);
    acc = mfma16(a2, load8(Wp + 64), acc);
    acc = mfma16(a3, load8(Wp + 96), acc);
    const float bv = ainb[col];
#pragma unroll
    for (int r = 0; r < 4; ++r)
      qkv[(long)(m0 + quad * 4 + r) * G3H + col] = f2bf(acc[r] + bv);
  }
}

// attention over C=4 cells; block = one batch elem, 128 thr = 4 heads x 32 dims
__global__ __launch_bounds__(128) void attn_kernel(const bf16* __restrict__ qkv,
                                                   bf16* __restrict__ o) {
  const int b = blockIdx.x;
  const int nh = threadIdx.x >> 5;
  const int d = threadIdx.x & 31;
  float q[C_], k[C_], v[C_];
#pragma unroll
  for (int c = 0; c < C_; ++c) {
    long base = ((long)c * B_ + b) * G3H + nh * 32 + d;
    q[c] = bf2f(qkv[base]);
    k[c] = bf2f(qkv[base + 128]);
    v[c] = bf2f(qkv[base + 256]);
  }
  float a[C_][C_];
#pragma unroll
  for (int qc = 0; qc < C_; ++qc) {
#pragma unroll
    for (int kc = 0; kc < C_; ++kc) {
      float p = q[qc] * k[kc];
#pragma unroll
      for (int off = 16; off; off >>= 1) p += __shfl_xor(p, off, 32);
      a[qc][kc] = p * 0.17677669529663687f;  // 1/sqrt(32)
    }
  }
#pragma unroll
  for (int qc = 0; qc < C_; ++qc) {
    float m = fmaxf(fmaxf(a[qc][0], a[qc][1]), fmaxf(a[qc][2], a[qc][3]));
    float s = 0.f;
#pragma unroll
    for (int kc = 0; kc < C_; ++kc) { a[qc][kc] = __expf(a[qc][kc] - m); s += a[qc][kc]; }
    float inv = 1.f / s;
    float ov = 0.f;
#pragma unroll
    for (int kc = 0; kc < C_; ++kc) ov += a[qc][kc] * v[kc];
    o[((long)qc * B_ + b) * H_ + nh * 32 + d] = f2bf(ov * inv);
  }
}

// ---------------------------------------------------------------------------
// Fused: o2 = o @ aoutw^T + aoutb (MFMA, LDS f32), LayerNorm, gate, blend.
// One block = 16 rows; 4 waves x 2 col-tiles; then each wave LNs 4 rows.
// hn (f32, d_out) read + overwritten in place.
// ---------------------------------------------------------------------------
__global__ __launch_bounds__(256) void oproj_ln_gate(const bf16* __restrict__ o,
                                                     const bf16* __restrict__ w,
                                                     const float* __restrict__ bias,
                                                     const float* __restrict__ g,
                                                     const float* __restrict__ bb,
                                                     const float* __restrict__ gatew,
                                                     const float* __restrict__ gateb,
                                                     float* __restrict__ hn) {
  __shared__ float o_s[16 * 132];
  const int wave = threadIdx.x >> 6, lane = threadIdx.x & 63;
  const int sub = lane & 15, quad = lane >> 4;
  const int m0 = blockIdx.x * 16;

  const bf16* Ap = o + (long)(m0 + sub) * H_ + quad * 8;
  bf16x8 a0 = load8(Ap), a1 = load8(Ap + 32), a2 = load8(Ap + 64), a3 = load8(Ap + 96);

#pragma unroll
  for (int t = 0; t < 2; ++t) {
    const int n0 = wave * 32 + t * 16;
    const bf16* Wp = w + (long)(n0 + sub) * H_ + quad * 8;
    floatx4 acc = {0.f, 0.f, 0.f, 0.f};
    acc = mfma16(a0, load8(Wp), acc);
    acc = mfma16(a1, load8(Wp + 32), acc);
    acc = mfma16(a2, load8(Wp + 64), acc);
    acc = mfma16(a3, load8(Wp + 96), acc);
    const int col = n0 + sub;
    const float bv = bias[col];
#pragma unroll
    for (int r = 0; r < 4; ++r) o_s[(quad * 4 + r) * 132 + col] = acc[r] + bv;
  }
  __syncthreads();

#pragma unroll
  for (int rr = 0; rr < 4; ++rr) {
    const int row = wave * 4 + rr;
    const int j1 = lane, j2 = lane + 64;
    float v1 = o_s[row * 132 + j1], v2 = o_s[row * 132 + j2];
    float mu = wave_sum(v1 + v2) * (1.f / 128.f);
    float d1 = v1 - mu, d2 = v2 - mu;
    float var = wave_sum(d1 * d1 + d2 * d2) * (1.f / 128.f);
    float rs = rsqrtf(var + 1e-5f);
    float m1 = d1 * rs * g[j1] + bb[j1];
    float m2 = d2 * rs * g[j2] + bb[j2];
    const long grow = m0 + row;
    float h1 = hn[grow * H_ + j1], h2 = hn[grow * H_ + j2];
    float gp = h1 * gatew[j1] + m1 * gatew[128 + j1] +
               h2 * gatew[j2] + m2 * gatew[128 + j2];
    float gt = 1.f / (1.f + __expf(-(wave_sum(gp) + gateb[0])));
    hn[grow * H_ + j1] = (1.f - gt) * h1 + gt * m1;
    hn[grow * H_ + j2] = (1.f - gt) * h2 + gt * m2;
  }
}

extern "C" void kernel_launch(void* const* d_in, const int* in_sizes, int n_in,
                              void* d_out, int out_size, void* d_ws, size_t ws_size,
                              hipStream_t stream) {
  const int*   tokens = (const int*)d_in[0];
  const float* h      = (const float*)d_in[1];
  const float* emb    = (const float*)d_in[2];
  const float* wih0c0 = (const float*)d_in[3];
  const float* bih0   = (const float*)d_in[5];
  const float* whh0   = (const float*)d_in[6];
  const float* bhh0   = (const float*)d_in[7];
  const float* wih    = (const float*)d_in[8];
  const float* whh    = (const float*)d_in[9];
  const float* bih    = (const float*)d_in[10];
  const float* bhh    = (const float*)d_in[11];
  const float* ainw   = (const float*)d_in[12];
  const float* ainb   = (const float*)d_in[13];
  const float* aoutw  = (const float*)d_in[14];
  const float* aoutb  = (const float*)d_in[15];
  const float* lng    = (const float*)d_in[16];
  const float* lnb    = (const float*)d_in[17];
  const float* gw     = (const float*)d_in[18];
  const float* gb     = (const float*)d_in[19];
  const float* headw  = (const float*)d_in[20];
  const float* headb  = (const float*)d_in[21];

  float* y_out  = (float*)d_out;                 // (B, O)
  float* hn_out = (float*)d_out + (long)B_ * O_; // (L, C, B, H)

  // workspace layout (bf16 elements), ~70 MiB total
  bf16* ws = (bf16*)d_ws;
  bf16* bufA = ws;                          // qkv: CB*384 = 48 MiB
  bf16* bufO = bufA + (long)CB * G3H;       // CB*128 = 16 MiB
  bf16* x0   = bufO;                        // aliases bufO (dead before first attn)
  bf16* wp   = bufO + (long)CB * H_;
  bf16* wih0bf  = wp;                  wp += 49152;   // 384*128
  bf16* whh0bf  = wp;                  wp += 196608;  // 4*384*128
  bf16* wihbf   = wp;                  wp += 983040;  // 5*4*384*128
  bf16* whhbf   = wp;                  wp += 983040;
  bf16* ainwbf  = wp;                  wp += 294912;  // 6*384*128
  bf16* aoutwbf = wp;                  wp += 98304;   // 6*128*128
  bf16* headwbf = wp;                  wp += 131072;  // 1024*128

  dim3 blk(256);
  auto cvt = [&](const float* src, bf16* dst, long n) {
    cvt_kernel<<<(int)((n + 255) / 256), blk, 0, stream>>>(src, dst, n);
  };
  cvt(wih0c0, wih0bf, 49152);
  cvt(whh0, whh0bf, 196608);
  cvt(wih, wihbf, 983040);
  cvt(whh, whhbf, 983040);
  cvt(ainw, ainwbf, 294912);
  cvt(aoutw, aoutwbf, 98304);
  cvt(headw, headwbf, 131072);

  embed_kernel<<<B_, 128, 0, stream>>>(tokens, emb, x0);

  for (int l = 0; l < L_; ++l) {
    float* hn_l = hn_out + (long)l * CBH;
    const float* hl = h + (long)l * CBH;

    // fused gi+gh+GRU+qkv -> hn_l (f32) + bufA (qkv bf16)
    if (l == 0) {
      cell_fused<true><<<CB / 16, blk, 0, stream>>>(
          nullptr, x0, wih0bf, bih0, hl, whh0bf, bhh0,
          ainwbf, ainb, hn_l, bufA);
    } else {
      cell_fused<false><<<CB / 16, blk, 0, stream>>>(
          hn_out + (long)(l - 1) * CBH, nullptr,
          wihbf + (long)(l - 1) * C_ * G3H * H_, bih + (long)(l - 1) * C_ * G3H,
          hl, whhbf + (long)(l - 1) * C_ * G3H * H_, bhh + (long)(l - 1) * C_ * G3H,
          ainwbf + (long)l * G3H * H_, ainb + (long)l * G3H, hn_l, bufA);
    }

    // attention -> bufO (bf16)
    attn_kernel<<<B_, 128, 0, stream>>>(bufA, bufO);

    // out-proj + LN + gate + blend -> hn_l (final, f32)
    oproj_ln_gate<<<CB / 16, blk, 0, stream>>>(
        bufO, aoutwbf + (long)l * H_ * H_, aoutb + (long)l * H_,
        lng + l * H_, lnb + l * H_, gw + l * 2 * H_, gb + l, hn_l);
  }

  // head: y = h_n[5, c=0] @ head_w^T + head_b
  gemm_bt<float, float><<<dim3(B_ / 16, O_ / 64), blk, 0, stream>>>(
      hn_out + (long)5 * CBH, headwbf, headb, y_out, O_, B_, 0, 0);
}

// Round 2
// 1468.126 us; speedup vs baseline: 1.2197x; 1.2197x over previous
//
#include <hip/hip_runtime.h>
#include <hip/hip_bf16.h>

// ---- problem constants ----
#define B_   16384
#define H_   128
#define C_   4
#define L_   6
#define O_   1024
#define G3H  384
#define CB   (C_ * B_)
#define CBH  (C_ * B_ * H_)

typedef __hip_bfloat16 bf16;
using bf16x8  = __attribute__((ext_vector_type(8))) __bf16;
using floatx4 = __attribute__((ext_vector_type(4))) float;

__device__ __forceinline__ bf16 f2bf(float x) { return __float2bfloat16(x); }
__device__ __forceinline__ float bf2f(bf16 x) { return __bfloat162float(x); }
__device__ __forceinline__ void store_val(float* p, float v) { *p = v; }
__device__ __forceinline__ void store_val(bf16* p, float v) { *p = f2bf(v); }

__device__ __forceinline__ floatx4 mfma16(bf16x8 a, bf16x8 b, floatx4 c) {
  return __builtin_amdgcn_mfma_f32_16x16x32_bf16(a, b, c, 0, 0, 0);
}

// fragment loaders: 8 consecutive K elements
__device__ __forceinline__ bf16x8 load8(const bf16* p) { return *(const bf16x8*)p; }
__device__ __forceinline__ bf16x8 load8(const float* p) {
  const float4 a = *(const float4*)p;
  const float4 b = *(const float4*)(p + 4);
  bf16x8 r;
  r[0] = (__bf16)a.x; r[1] = (__bf16)a.y; r[2] = (__bf16)a.z; r[3] = (__bf16)a.w;
  r[4] = (__bf16)b.x; r[5] = (__bf16)b.y; r[6] = (__bf16)b.z; r[7] = (__bf16)b.w;
  return r;
}

__device__ __forceinline__ float wave_sum(float x) {
#pragma unroll
  for (int off = 32; off; off >>= 1) x += __shfl_xor(x, off);
  return x;
}

__device__ __forceinline__ float sigmoidf_(float x) {
  return 1.f / (1.f + __expf(-x));
}
// tanh via exp2-backed __expf; exact at +/-inf saturation
__device__ __forceinline__ float tanhf_(float x) {
  float e = __expf(2.f * x);
  return 1.f - 2.f / (e + 1.f);
}

// f32 -> bf16 conversion (weights, once per launch)
__global__ __launch_bounds__(256) void cvt_kernel(const float* __restrict__ in,
                                                  bf16* __restrict__ out, long n) {
  long i = (long)blockIdx.x * 256 + threadIdx.x;
  if (i < n) out[i] = f2bf(in[i]);
}

// ---------------------------------------------------------------------------
// Generic GEMM (head only now): out[r, n] = sum_k A[r,k] * W[n,k] + bias[n]
// Fragment layouts (m89-verified):
//   A/B frag: m|n = lane&15, k = (lane>>4)*8 + j
//   C/D:      col(n) = lane&15, row(m) = (lane>>4)*4 + reg
// ---------------------------------------------------------------------------
template <typename AT, typename OutT>
__global__ __launch_bounds__(256) void gemm_bt(const AT* __restrict__ A,
                                               const bf16* __restrict__ W,
                                               const float* __restrict__ bias,
                                               OutT* __restrict__ out,
                                               int N, int rows_per_batch,
                                               long wstride, long bstride) {
  const int wave = threadIdx.x >> 6;
  const int lane = threadIdx.x & 63;
  const int m0   = blockIdx.x * 16;
  const int n0   = blockIdx.y * 64 + wave * 16;
  const int sub  = lane & 15;
  const int quad = lane >> 4;
  const int batch = m0 / rows_per_batch;
  const bf16*  Wb = W + (long)batch * wstride;
  const float* Bi = bias + (long)batch * bstride;

  const AT*   Ap = A + (long)(m0 + sub) * 128 + quad * 8;
  const bf16* Wp = Wb + (long)(n0 + sub) * 128 + quad * 8;

  floatx4 acc = {0.f, 0.f, 0.f, 0.f};
#pragma unroll
  for (int kc = 0; kc < 4; ++kc) {
    acc = mfma16(load8(Ap + kc * 32), load8(Wp + kc * 32), acc);
  }

  const int col = n0 + sub;
  const float bv = Bi[col];
#pragma unroll
  for (int r = 0; r < 4; ++r) {
    long row = m0 + quad * 4 + r;
    store_val(&out[row * (long)N + col], acc[r] + bv);
  }
}

// x0[b,:] = bf16(emb[tokens[b],:])
__global__ __launch_bounds__(128) void embed_kernel(const int* __restrict__ tok,
                                                    const float* __restrict__ emb,
                                                    bf16* __restrict__ x0) {
  const int b = blockIdx.x;
  x0[(long)b * 128 + threadIdx.x] = f2bf(emb[(long)tok[b] * 128 + threadIdx.x]);
}

// ---------------------------------------------------------------------------
// Fused per-cell kernel, v2 (32-row blocks, GRU in registers).
// Block = 32 rows of (c,b), 4 waves. Per wave: 2 row-tiles of 16, A-fragments
// for h and x held in registers and reused across all weight col-tiles
// (weight load : MFMA = 1:2, 6 indep acc chains per kc step for ILP).
// Column->wave mapping gives GRU lane-locality: wave w owns output cols
// [32w, 32w+32); its r/z/n pre-activations live in the same lane (r,z
// co-accumulated via the MFMA C-operand). GRU is pure-register; hn goes to
// global f32 + an XOR-swizzled 8KB LDS tile (T2, byte^=(row&7)<<4) that
// feeds conflict-optimal ds_read_b128 A-fragments for the fused qkv GEMM.
// L0: layer-0 (cell0 A = x0 bf16; cells 1-3 gi = bias broadcast).
// ---------------------------------------------------------------------------
template <bool L0>
__global__ __launch_bounds__(256) void cell_fused(const float* __restrict__ x,
                                                  const bf16* __restrict__ x0,
                                                  const bf16* __restrict__ wih_l,
                                                  const float* __restrict__ bih_l,
                                                  const float* __restrict__ h,
                                                  const bf16* __restrict__ whh_l,
                                                  const float* __restrict__ bhh_l,
                                                  const bf16* __restrict__ ainw,
                                                  const float* __restrict__ ainb,
                                                  float* __restrict__ hn,
                                                  bf16* __restrict__ qkv) {
  __shared__ char hn_raw[32 * 256];  // 32 rows x 128 bf16, XOR-swizzled

  const int wave = threadIdx.x >> 6, lane = threadIdx.x & 63;
  const int sub = lane & 15, quad = lane >> 4;
  const int m0 = blockIdx.x * 32;
  const int cell = m0 / B_;
  const bool has_gi = (!L0) || (cell == 0);

  const bf16*  Wh = whh_l + (long)cell * G3H * H_;
  const bf16*  Wi = L0 ? wih_l : wih_l + (long)cell * G3H * H_;
  const float* bh = bhh_l + cell * G3H;
  const float* bi = bih_l + cell * G3H;

  // A fragments (held in registers for the whole GEMM1 phase)
  bf16x8 hf[2][4], xf[2][4];
#pragma unroll
  for (int rt = 0; rt < 2; ++rt) {
    const float* Hp = h + (long)(m0 + rt * 16 + sub) * H_ + quad * 8;
#pragma unroll
    for (int kc = 0; kc < 4; ++kc) hf[rt][kc] = load8(Hp + kc * 32);
  }
  if (has_gi) {
    if constexpr (L0) {
#pragma unroll
      for (int rt = 0; rt < 2; ++rt) {
        const bf16* Xp = x0 + (long)(m0 + rt * 16 + sub) * H_ + quad * 8;
#pragma unroll
        for (int kc = 0; kc < 4; ++kc) xf[rt][kc] = load8(Xp + kc * 32);
      }
    } else {
#pragma unroll
      for (int rt = 0; rt < 2; ++rt) {
        const float* Xp = x + (long)(m0 + rt * 16 + sub) * H_ + quad * 8;
#pragma unroll
        for (int kc = 0; kc < 4; ++kc) xf[rt][kc] = load8(Xp + kc * 32);
      }
    }
  }

  // two column passes: wave w, pass tt covers output cols wave*32+tt*16+[0,16)
#pragma unroll
  for (int tt = 0; tt < 2; ++tt) {
    const int colr = wave * 32 + tt * 16 + sub;  // output col in [0,128)
    floatx4 ar[2], az[2], anh[2], ani[2];
#pragma unroll
    for (int rt = 0; rt < 2; ++rt) {
      ar[rt] = floatx4{0.f, 0.f, 0.f, 0.f};
      az[rt] = floatx4{0.f, 0.f, 0.f, 0.f};
      anh[rt] = floatx4{0.f, 0.f, 0.f, 0.f};
      ani[rt] = floatx4{0.f, 0.f, 0.f, 0.f};
    }

    const bf16* Whr = Wh + (long)colr * H_ + quad * 8;
#pragma unroll
    for (int kc = 0; kc < 4; ++kc) {
      bf16x8 wr = load8(Whr + kc * 32);
      bf16x8 wz = load8(Whr + 128 * H_ + kc * 32);
      bf16x8 wn = load8(Whr + 256 * H_ + kc * 32);
      ar[0]  = mfma16(hf[0][kc], wr, ar[0]);
      ar[1]  = mfma16(hf[1][kc], wr, ar[1]);
      az[0]  = mfma16(hf[0][kc], wz, az[0]);
      az[1]  = mfma16(hf[1][kc], wz, az[1]);
      anh[0] = mfma16(hf[0][kc], wn, anh[0]);
      anh[1] = mfma16(hf[1][kc], wn, anh[1]);
    }
    if (has_gi) {
      const bf16* Wir = Wi + (long)colr * H_ + quad * 8;
#pragma unroll
      for (int kc = 0; kc < 4; ++kc) {
        bf16x8 wr = load8(Wir + kc * 32);
        bf16x8 wz = load8(Wir + 128 * H_ + kc * 32);
        bf16x8 wn = load8(Wir + 256 * H_ + kc * 32);
        ar[0]  = mfma16(xf[0][kc], wr, ar[0]);   // r: gi+gh co-accumulated
        ar[1]  = mfma16(xf[1][kc], wr, ar[1]);
        az[0]  = mfma16(xf[0][kc], wz, az[0]);   // z: gi+gh co-accumulated
        az[1]  = mfma16(xf[1][kc], wz, az[1]);
        ani[0] = mfma16(xf[0][kc], wn, ani[0]);  // n: kept separate
        ani[1] = mfma16(xf[1][kc], wn, ani[1]);
      }
    }

    const float bir = bi[colr], bhr = bh[colr];
    const float biz = bi[128 + colr], bhz = bh[128 + colr];
    const float bin_ = bi[256 + colr], bhn = bh[256 + colr];

    // GRU elementwise, fully in registers (C/D layout: row=quad*4+r, col=colr)
#pragma unroll
    for (int rt = 0; rt < 2; ++rt) {
      const long rowg = m0 + rt * 16 + quad * 4;
#pragma unroll
      for (int r = 0; r < 4; ++r) {
        float rg = sigmoidf_(ar[rt][r] + bir + bhr);
        float zg = sigmoidf_(az[rt][r] + biz + bhz);
        float ng = tanhf_(ani[rt][r] + bin_ + rg * (anh[rt][r] + bhn));
        float hv = h[(rowg + r) * H_ + colr];
        float hnv = (1.f - zg) * ng + zg * hv;
        hn[(rowg + r) * H_ + colr] = hnv;
        const int lrow = rt * 16 + quad * 4 + r;
        const int boff = (lrow * 256 + colr * 2) ^ ((lrow & 7) << 4);
        *(bf16*)(hn_raw + boff) = f2bf(hnv);
      }
    }
  }
  __syncthreads();

  // qkv GEMM: A = hn (bf16, swizzled LDS), W = ainw. Wave w: cols [96w,96w+96)
  bf16x8 af[2][4];
#pragma unroll
  for (int rt = 0; rt < 2; ++rt) {
#pragma unroll
    for (int kc = 0; kc < 4; ++kc) {
      const int lrow = rt * 16 + sub;
      const int boff = (lrow * 256 + kc * 64 + quad * 16) ^ ((lrow & 7) << 4);
      af[rt][kc] = *(const bf16x8*)(hn_raw + boff);
    }
  }
#pragma unroll
  for (int t = 0; t < 6; ++t) {
    const int col = wave * 96 + t * 16 + sub;
    const bf16* Wp = ainw + (long)col * H_ + quad * 8;
    floatx4 acc0 = {0.f, 0.f, 0.f, 0.f}, acc1 = {0.f, 0.f, 0.f, 0.f};
#pragma unroll
    for (int kc = 0; kc < 4; ++kc) {
      bf16x8 wv = load8(Wp + kc * 32);
      acc0 = mfma16(af[0][kc], wv, acc0);
      acc1 = mfma16(af[1][kc], wv, acc1);
    }
    const float bv = ainb[col];
#pragma unroll
    for (int r = 0; r < 4; ++r) {
      qkv[(long)(m0 + quad * 4 + r) * G3H + col] = f2bf(acc0[r] + bv);
      qkv[(long)(m0 + 16 + quad * 4 + r) * G3H + col] = f2bf(acc1[r] + bv);
    }
  }
}

// attention over C=4 cells; block = one batch elem, 128 thr = 4 heads x 32 dims
__global__ __launch_bounds__(128) void attn_kernel(const bf16* __restrict__ qkv,
                                                   bf16* __restrict__ o) {
  const int b = blockIdx.x;
  const int nh = threadIdx.x >> 5;
  const int d = threadIdx.x & 31;
  float q[C_], k[C_], v[C_];
#pragma unroll
  for (int c = 0; c < C_; ++c) {
    long base = ((long)c * B_ + b) * G3H + nh * 32 + d;
    q[c] = bf2f(qkv[base]);
    k[c] = bf2f(qkv[base + 128]);
    v[c] = bf2f(qkv[base + 256]);
  }
  float a[C_][C_];
#pragma unroll
  for (int qc = 0; qc < C_; ++qc) {
#pragma unroll
    for (int kc = 0; kc < C_; ++kc) {
      float p = q[qc] * k[kc];
#pragma unroll
      for (int off = 16; off; off >>= 1) p += __shfl_xor(p, off, 32);
      a[qc][kc] = p * 0.17677669529663687f;  // 1/sqrt(32)
    }
  }
#pragma unroll
  for (int qc = 0; qc < C_; ++qc) {
    float m = fmaxf(fmaxf(a[qc][0], a[qc][1]), fmaxf(a[qc][2], a[qc][3]));
    float s = 0.f;
#pragma unroll
    for (int kc = 0; kc < C_; ++kc) { a[qc][kc] = __expf(a[qc][kc] - m); s += a[qc][kc]; }
    float inv = 1.f / s;
    float ov = 0.f;
#pragma unroll
    for (int kc = 0; kc < C_; ++kc) ov += a[qc][kc] * v[kc];
    o[((long)qc * B_ + b) * H_ + nh * 32 + d] = f2bf(ov * inv);
  }
}

// ---------------------------------------------------------------------------
// Fused: o2 = o @ aoutw^T + aoutb (MFMA, LDS f32), LayerNorm, gate, blend.
// One block = 16 rows; 4 waves x 2 col-tiles; then each wave LNs 4 rows.
// hn (f32, d_out) read + overwritten in place.
// ---------------------------------------------------------------------------
__global__ __launch_bounds__(256) void oproj_ln_gate(const bf16* __restrict__ o,
                                                     const bf16* __restrict__ w,
                                                     const float* __restrict__ bias,
                                                     const float* __restrict__ g,
                                                     const float* __restrict__ bb,
                                                     const float* __restrict__ gatew,
                                                     const float* __restrict__ gateb,
                                                     float* __restrict__ hn) {
  __shared__ float o_s[16 * 132];
  const int wave = threadIdx.x >> 6, lane = threadIdx.x & 63;
  const int sub = lane & 15, quad = lane >> 4;
  const int m0 = blockIdx.x * 16;

  const bf16* Ap = o + (long)(m0 + sub) * H_ + quad * 8;
  bf16x8 a0 = load8(Ap), a1 = load8(Ap + 32), a2 = load8(Ap + 64), a3 = load8(Ap + 96);

#pragma unroll
  for (int t = 0; t < 2; ++t) {
    const int n0 = wave * 32 + t * 16;
    const bf16* Wp = w + (long)(n0 + sub) * H_ + quad * 8;
    floatx4 acc = {0.f, 0.f, 0.f, 0.f};
    acc = mfma16(a0, load8(Wp), acc);
    acc = mfma16(a1, load8(Wp + 32), acc);
    acc = mfma16(a2, load8(Wp + 64), acc);
    acc = mfma16(a3, load8(Wp + 96), acc);
    const int col = n0 + sub;
    const float bv = bias[col];
#pragma unroll
    for (int r = 0; r < 4; ++r) o_s[(quad * 4 + r) * 132 + col] = acc[r] + bv;
  }
  __syncthreads();

#pragma unroll
  for (int rr = 0; rr < 4; ++rr) {
    const int row = wave * 4 + rr;
    const int j1 = lane, j2 = lane + 64;
    float v1 = o_s[row * 132 + j1], v2 = o_s[row * 132 + j2];
    float mu = wave_sum(v1 + v2) * (1.f / 128.f);
    float d1 = v1 - mu, d2 = v2 - mu;
    float var = wave_sum(d1 * d1 + d2 * d2) * (1.f / 128.f);
    float rs = rsqrtf(var + 1e-5f);
    float m1 = d1 * rs * g[j1] + bb[j1];
    float m2 = d2 * rs * g[j2] + bb[j2];
    const long grow = m0 + row;
    float h1 = hn[grow * H_ + j1], h2 = hn[grow * H_ + j2];
    float gp = h1 * gatew[j1] + m1 * gatew[128 + j1] +
               h2 * gatew[j2] + m2 * gatew[128 + j2];
    float gt = 1.f / (1.f + __expf(-(wave_sum(gp) + gateb[0])));
    hn[grow * H_ + j1] = (1.f - gt) * h1 + gt * m1;
    hn[grow * H_ + j2] = (1.f - gt) * h2 + gt * m2;
  }
}

extern "C" void kernel_launch(void* const* d_in, const int* in_sizes, int n_in,
                              void* d_out, int out_size, void* d_ws, size_t ws_size,
                              hipStream_t stream) {
  const int*   tokens = (const int*)d_in[0];
  const float* h      = (const float*)d_in[1];
  const float* emb    = (const float*)d_in[2];
  const float* wih0c0 = (const float*)d_in[3];
  const float* bih0   = (const float*)d_in[5];
  const float* whh0   = (const float*)d_in[6];
  const float* bhh0   = (const float*)d_in[7];
  const float* wih    = (const float*)d_in[8];
  const float* whh    = (const float*)d_in[9];
  const float* bih    = (const float*)d_in[10];
  const float* bhh    = (const float*)d_in[11];
  const float* ainw   = (const float*)d_in[12];
  const float* ainb   = (const float*)d_in[13];
  const float* aoutw  = (const float*)d_in[14];
  const float* aoutb  = (const float*)d_in[15];
  const float* lng    = (const float*)d_in[16];
  const float* lnb    = (const float*)d_in[17];
  const float* gw     = (const float*)d_in[18];
  const float* gb     = (const float*)d_in[19];
  const float* headw  = (const float*)d_in[20];
  const float* headb  = (const float*)d_in[21];

  float* y_out  = (float*)d_out;                 // (B, O)
  float* hn_out = (float*)d_out + (long)B_ * O_; // (L, C, B, H)

  // workspace layout (bf16 elements), ~70 MiB total
  bf16* ws = (bf16*)d_ws;
  bf16* bufA = ws;                          // qkv: CB*384 = 48 MiB
  bf16* bufO = bufA + (long)CB * G3H;       // CB*128 = 16 MiB
  bf16* x0   = bufO;                        // aliases bufO (dead before first attn)
  bf16* wp   = bufO + (long)CB * H_;
  bf16* wih0bf  = wp;                  wp += 49152;   // 384*128
  bf16* whh0bf  = wp;                  wp += 196608;  // 4*384*128
  bf16* wihbf   = wp;                  wp += 983040;  // 5*4*384*128
  bf16* whhbf   = wp;                  wp += 983040;
  bf16* ainwbf  = wp;                  wp += 294912;  // 6*384*128
  bf16* aoutwbf = wp;                  wp += 98304;   // 6*128*128
  bf16* headwbf = wp;                  wp += 131072;  // 1024*128

  dim3 blk(256);
  auto cvt = [&](const float* src, bf16* dst, long n) {
    cvt_kernel<<<(int)((n + 255) / 256), blk, 0, stream>>>(src, dst, n);
  };
  cvt(wih0c0, wih0bf, 49152);
  cvt(whh0, whh0bf, 196608);
  cvt(wih, wihbf, 983040);
  cvt(whh, whhbf, 983040);
  cvt(ainw, ainwbf, 294912);
  cvt(aoutw, aoutwbf, 98304);
  cvt(headw, headwbf, 131072);

  embed_kernel<<<B_, 128, 0, stream>>>(tokens, emb, x0);

  for (int l = 0; l < L_; ++l) {
    float* hn_l = hn_out + (long)l * CBH;
    const float* hl = h + (long)l * CBH;

    // fused gi+gh+GRU+qkv -> hn_l (f32) + bufA (qkv bf16)
    if (l == 0) {
      cell_fused<true><<<CB / 32, blk, 0, stream>>>(
          nullptr, x0, wih0bf, bih0, hl, whh0bf, bhh0,
          ainwbf, ainb, hn_l, bufA);
    } else {
      cell_fused<false><<<CB / 32, blk, 0, stream>>>(
          hn_out + (long)(l - 1) * CBH, nullptr,
          wihbf + (long)(l - 1) * C_ * G3H * H_, bih + (long)(l - 1) * C_ * G3H,
          hl, whhbf + (long)(l - 1) * C_ * G3H * H_, bhh + (long)(l - 1) * C_ * G3H,
          ainwbf + (long)l * G3H * H_, ainb + (long)l * G3H, hn_l, bufA);
    }

    // attention -> bufO (bf16)
    attn_kernel<<<B_, 128, 0, stream>>>(bufA, bufO);

    // out-proj + LN + gate + blend -> hn_l (final, f32)
    oproj_ln_gate<<<CB / 16, blk, 0, stream>>>(
        bufO, aoutwbf + (long)l * H_ * H_, aoutb + (long)l * H_,
        lng + l * H_, lnb + l * H_, gw + l * 2 * H_, gb + l, hn_l);
  }

  // head: y = h_n[5, c=0] @ head_w^T + head_b
  gemm_bt<float, float><<<dim3(B_ / 16, O_ / 64), blk, 0, stream>>>(
      hn_out + (long)5 * CBH, headwbf, headb, y_out, O_, B_, 0, 0);
}

// Round 3
// 1287.857 us; speedup vs baseline: 1.3904x; 1.1400x over previous
//
#include <hip/hip_runtime.h>
#include <hip/hip_bf16.h>

// ---- problem constants ----
#define B_   16384
#define H_   128
#define C_   4
#define L_   6
#define O_   1024
#define G3H  384
#define CB   (C_ * B_)
#define CBH  (C_ * B_ * H_)

typedef __hip_bfloat16 bf16;
using bf16x8  = __attribute__((ext_vector_type(8))) __bf16;
using bf16x4  = __attribute__((ext_vector_type(4))) __bf16;
using floatx4 = __attribute__((ext_vector_type(4))) float;

__device__ __forceinline__ bf16 f2bf(float x) { return __float2bfloat16(x); }
__device__ __forceinline__ float bf2f(bf16 x) { return __bfloat162float(x); }
__device__ __forceinline__ void store_val(float* p, float v) { *p = v; }
__device__ __forceinline__ void store_val(bf16* p, float v) { *p = f2bf(v); }

__device__ __forceinline__ floatx4 mfma16(bf16x8 a, bf16x8 b, floatx4 c) {
  return __builtin_amdgcn_mfma_f32_16x16x32_bf16(a, b, c, 0, 0, 0);
}

// fragment loaders: 8 consecutive K elements
__device__ __forceinline__ bf16x8 load8(const bf16* p) { return *(const bf16x8*)p; }
__device__ __forceinline__ bf16x8 load8(const float* p) {
  const float4 a = *(const float4*)p;
  const float4 b = *(const float4*)(p + 4);
  bf16x8 r;
  r[0] = (__bf16)a.x; r[1] = (__bf16)a.y; r[2] = (__bf16)a.z; r[3] = (__bf16)a.w;
  r[4] = (__bf16)b.x; r[5] = (__bf16)b.y; r[6] = (__bf16)b.z; r[7] = (__bf16)b.w;
  return r;
}

__device__ __forceinline__ float wave_sum(float x) {
#pragma unroll
  for (int off = 32; off; off >>= 1) x += __shfl_xor(x, off);
  return x;
}

__device__ __forceinline__ float sigmoidf_(float x) {
  return 1.f / (1.f + __expf(-x));
}
// tanh via exp2-backed __expf; exact at +/-inf saturation
__device__ __forceinline__ float tanhf_(float x) {
  float e = __expf(2.f * x);
  return 1.f - 2.f / (e + 1.f);
}

// single-launch weight conversion: 7 contiguous dst segments (4-elem units)
struct Cvt7 {
  const float* src[7];
  long start4[8];  // cumulative lengths / 4
};
__global__ __launch_bounds__(256) void cvt7_kernel(Cvt7 a, bf16* __restrict__ dst) {
  long i4 = (long)blockIdx.x * 256 + threadIdx.x;
  if (i4 >= a.start4[7]) return;
  int s = 0;
#pragma unroll
  for (int k = 1; k < 7; ++k)
    if (i4 >= a.start4[k]) s = k;
  const float4 v = ((const float4*)a.src[s])[i4 - a.start4[s]];
  bf16x4 o;
  o[0] = (__bf16)v.x; o[1] = (__bf16)v.y; o[2] = (__bf16)v.z; o[3] = (__bf16)v.w;
  ((bf16x4*)dst)[i4] = o;
}

// ---------------------------------------------------------------------------
// Generic GEMM (head only): out[r, n] = sum_k A[r,k] * W[n,k] + bias[n]
// Fragment layouts (m89-verified):
//   A/B frag: m|n = lane&15, k = (lane>>4)*8 + j
//   C/D:      col(n) = lane&15, row(m) = (lane>>4)*4 + reg
// ---------------------------------------------------------------------------
template <typename AT, typename OutT>
__global__ __launch_bounds__(256) void gemm_bt(const AT* __restrict__ A,
                                               const bf16* __restrict__ W,
                                               const float* __restrict__ bias,
                                               OutT* __restrict__ out,
                                               int N, int rows_per_batch,
                                               long wstride, long bstride) {
  const int wave = threadIdx.x >> 6;
  const int lane = threadIdx.x & 63;
  const int m0   = blockIdx.x * 16;
  const int n0   = blockIdx.y * 64 + wave * 16;
  const int sub  = lane & 15;
  const int quad = lane >> 4;
  const int batch = m0 / rows_per_batch;
  const bf16*  Wb = W + (long)batch * wstride;
  const float* Bi = bias + (long)batch * bstride;

  const AT*   Ap = A + (long)(m0 + sub) * 128 + quad * 8;
  const bf16* Wp = Wb + (long)(n0 + sub) * 128 + quad * 8;

  floatx4 acc = {0.f, 0.f, 0.f, 0.f};
#pragma unroll
  for (int kc = 0; kc < 4; ++kc) {
    acc = mfma16(load8(Ap + kc * 32), load8(Wp + kc * 32), acc);
  }

  const int col = n0 + sub;
  const float bv = Bi[col];
#pragma unroll
  for (int r = 0; r < 4; ++r) {
    long row = m0 + quad * 4 + r;
    store_val(&out[row * (long)N + col], acc[r] + bv);
  }
}

// x0[b,:] = bf16(emb[tokens[b],:])
__global__ __launch_bounds__(128) void embed_kernel(const int* __restrict__ tok,
                                                    const float* __restrict__ emb,
                                                    bf16* __restrict__ x0) {
  const int b = blockIdx.x;
  x0[(long)b * 128 + threadIdx.x] = f2bf(emb[(long)tok[b] * 128 + threadIdx.x]);
}

// ---------------------------------------------------------------------------
// Fused per-cell kernel, v3: 64-row blocks, LDS-staged activations.
// Block = 64 rows (c,b), 4 waves.  Phases:
//  S) stage h (and x) f32->bf16 into XOR-swizzled LDS tiles (coalesced).
//  1) GEMM1: wave w owns cols [32w,32w+32) of each gate third; per col pass
//     loads 24 weight frags (held in regs, ~96 VGPR) reused over 4 row-tiles
//     read from LDS -> MFMA:global-load = 8:1.  r,z co-accumulate gi+gh.
//  2) GRU fully in registers -> hn f32 global + bf16 swizzled LDS tile.
//  3) qkv GEMM: A from hn LDS tile, wave w cols [96w,96w+96).
// Swizzle: byte ^= (row&7)<<4 within 256B rows (uniform bank residues for
// both ds_write staging and ds_read_b128 fragment reads).
// L0: layer-0 (cell0 A = x0 bf16; cells 1-3 gi = bias broadcast).
// ---------------------------------------------------------------------------
template <bool L0>
__global__ __launch_bounds__(256) void cell_fused(const float* __restrict__ x,
                                                  const bf16* __restrict__ x0,
                                                  const bf16* __restrict__ wih_l,
                                                  const float* __restrict__ bih_l,
                                                  const float* __restrict__ h,
                                                  const bf16* __restrict__ whh_l,
                                                  const float* __restrict__ bhh_l,
                                                  const bf16* __restrict__ ainw,
                                                  const float* __restrict__ ainb,
                                                  float* __restrict__ hn,
                                                  bf16* __restrict__ qkv) {
  __shared__ __align__(16) char lds[3 * 16384];
  char* h_raw  = lds;             // 64 x 256B bf16, swizzled
  char* x_raw  = lds + 16384;
  char* hn_raw = lds + 32768;

  const int tid = threadIdx.x;
  const int wave = tid >> 6, lane = tid & 63;
  const int sub = lane & 15, quad = lane >> 4;
  const int m0 = blockIdx.x * 64;
  const int cell = m0 / B_;
  const bool has_gi = (!L0) || (cell == 0);

  // ---- phase S: stage activations ----
  {
    const int colg = tid & 15;   // 8-col group
    const int rb   = tid >> 4;   // 0..15
#pragma unroll
    for (int i = 0; i < 4; ++i) {
      const int row = i * 16 + rb;
      bf16x8 v = load8(h + (long)(m0 + row) * H_ + colg * 8);
      const int boff = (row * 256 + colg * 16) ^ ((row & 7) << 4);
      *(bf16x8*)(h_raw + boff) = v;
    }
    if (has_gi) {
      if constexpr (L0) {
#pragma unroll
        for (int i = 0; i < 4; ++i) {
          const int row = i * 16 + rb;
          bf16x8 v = load8(x0 + (long)(m0 + row) * H_ + colg * 8);
          const int boff = (row * 256 + colg * 16) ^ ((row & 7) << 4);
          *(bf16x8*)(x_raw + boff) = v;
        }
      } else {
#pragma unroll
        for (int i = 0; i < 4; ++i) {
          const int row = i * 16 + rb;
          bf16x8 v = load8(x + (long)(m0 + row) * H_ + colg * 8);
          const int boff = (row * 256 + colg * 16) ^ ((row & 7) << 4);
          *(bf16x8*)(x_raw + boff) = v;
        }
      }
    }
  }
  __syncthreads();

  const bf16*  Wh = whh_l + (long)cell * G3H * H_;
  const bf16*  Wi = L0 ? wih_l : wih_l + (long)cell * G3H * H_;
  const float* bh = bhh_l + cell * G3H;
  const float* bi = bih_l + cell * G3H;

  // ---- phases 1+2: GEMM1 + GRU ----
#pragma unroll
  for (int p = 0; p < 2; ++p) {
    const int colr = wave * 32 + p * 16 + sub;  // output col in [0,128)

    bf16x8 wfr[3][4], wif[3][4];
#pragma unroll
    for (int g = 0; g < 3; ++g) {
      const bf16* Wg = Wh + (long)(g * 128 + colr) * H_ + quad * 8;
#pragma unroll
      for (int kc = 0; kc < 4; ++kc) wfr[g][kc] = load8(Wg + kc * 32);
    }
    if (has_gi) {
#pragma unroll
      for (int g = 0; g < 3; ++g) {
        const bf16* Wg = Wi + (long)(g * 128 + colr) * H_ + quad * 8;
#pragma unroll
        for (int kc = 0; kc < 4; ++kc) wif[g][kc] = load8(Wg + kc * 32);
      }
    }

    const float bir = bi[colr],        bhr = bh[colr];
    const float biz = bi[128 + colr],  bhz = bh[128 + colr];
    const float bin_ = bi[256 + colr], bhn = bh[256 + colr];

#pragma unroll
    for (int rt = 0; rt < 4; ++rt) {
      bf16x8 hfr[4];
#pragma unroll
      for (int kc = 0; kc < 4; ++kc) {
        const int lrow = rt * 16 + sub;
        const int boff = (lrow * 256 + kc * 64 + quad * 16) ^ ((lrow & 7) << 4);
        hfr[kc] = *(const bf16x8*)(h_raw + boff);
      }
      floatx4 ar = {0.f, 0.f, 0.f, 0.f}, az = {0.f, 0.f, 0.f, 0.f};
      floatx4 anh = {0.f, 0.f, 0.f, 0.f}, ani = {0.f, 0.f, 0.f, 0.f};
#pragma unroll
      for (int kc = 0; kc < 4; ++kc) {
        ar  = mfma16(hfr[kc], wfr[0][kc], ar);
        az  = mfma16(hfr[kc], wfr[1][kc], az);
        anh = mfma16(hfr[kc], wfr[2][kc], anh);
      }
      if (has_gi) {
        bf16x8 xfr[4];
#pragma unroll
        for (int kc = 0; kc < 4; ++kc) {
          const int lrow = rt * 16 + sub;
          const int boff = (lrow * 256 + kc * 64 + quad * 16) ^ ((lrow & 7) << 4);
          xfr[kc] = *(const bf16x8*)(x_raw + boff);
        }
#pragma unroll
        for (int kc = 0; kc < 4; ++kc) {
          ar  = mfma16(xfr[kc], wif[0][kc], ar);   // r: gi+gh co-accumulated
          az  = mfma16(xfr[kc], wif[1][kc], az);   // z: gi+gh co-accumulated
          ani = mfma16(xfr[kc], wif[2][kc], ani);  // n: kept separate
        }
      }

      // GRU elementwise (C/D layout: row = rt*16 + quad*4 + r, col = colr)
#pragma unroll
      for (int r = 0; r < 4; ++r) {
        const int lrow = rt * 16 + quad * 4 + r;
        const long grow = m0 + lrow;
        float rg = sigmoidf_(ar[r] + bir + bhr);
        float zg = sigmoidf_(az[r] + biz + bhz);
        float ng = tanhf_(ani[r] + bin_ + rg * (anh[r] + bhn));
        float hv = h[grow * H_ + colr];
        float hnv = (1.f - zg) * ng + zg * hv;
        hn[grow * H_ + colr] = hnv;
        const int boff = (lrow * 256 + colr * 2) ^ ((lrow & 7) << 4);
        *(bf16*)(hn_raw + boff) = f2bf(hnv);
      }
    }
  }
  __syncthreads();

  // ---- phase 3: qkv GEMM (A = hn LDS tile) ----
#pragma unroll
  for (int t = 0; t < 6; ++t) {
    const int col = wave * 96 + t * 16 + sub;
    bf16x8 wf[4];
    const bf16* Wp = ainw + (long)col * H_ + quad * 8;
#pragma unroll
    for (int kc = 0; kc < 4; ++kc) wf[kc] = load8(Wp + kc * 32);
    const float bv = ainb[col];
#pragma unroll
    for (int rp = 0; rp < 2; ++rp) {  // row-tile pairs for 2 indep MFMA chains
      bf16x8 af0[4], af1[4];
#pragma unroll
      for (int kc = 0; kc < 4; ++kc) {
        const int lr0 = (2 * rp) * 16 + sub, lr1 = (2 * rp + 1) * 16 + sub;
        af0[kc] = *(const bf16x8*)(hn_raw +
                   ((lr0 * 256 + kc * 64 + quad * 16) ^ ((lr0 & 7) << 4)));
        af1[kc] = *(const bf16x8*)(hn_raw +
                   ((lr1 * 256 + kc * 64 + quad * 16) ^ ((lr1 & 7) << 4)));
      }
      floatx4 acc0 = {0.f, 0.f, 0.f, 0.f}, acc1 = {0.f, 0.f, 0.f, 0.f};
#pragma unroll
      for (int kc = 0; kc < 4; ++kc) {
        acc0 = mfma16(af0[kc], wf[kc], acc0);
        acc1 = mfma16(af1[kc], wf[kc], acc1);
      }
#pragma unroll
      for (int r = 0; r < 4; ++r) {
        qkv[(long)(m0 + (2 * rp) * 16 + quad * 4 + r) * G3H + col] = f2bf(acc0[r] + bv);
        qkv[(long)(m0 + (2 * rp + 1) * 16 + quad * 4 + r) * G3H + col] = f2bf(acc1[r] + bv);
      }
    }
  }
}

// ---------------------------------------------------------------------------
// Fused attention + out-proj + LN + gate + blend.
// Block = 16 batch elems x 4 cells = 64 o-rows, 256 threads.
//  A) stage qkv tile (64 x 384 bf16, 48KB) to LDS, coalesced.
//  B) attention per (b, head) pair (8 pairs/iter x 8 iters), shuffle dots over
//     d=32; o written to XOR-swizzled LDS tile (never touches global).
//  C) oproj GEMM: 64 rows per weight load (4:1), o2 -> LDS f32 (aliases qkv_s).
//  D) LN + gate + blend per row (wave_sum), hn f32 in place.
// ---------------------------------------------------------------------------
__global__ __launch_bounds__(256) void attn_oproj(const bf16* __restrict__ qkv,
                                                  const bf16* __restrict__ w,
                                                  const float* __restrict__ bias,
                                                  const float* __restrict__ g,
                                                  const float* __restrict__ bb,
                                                  const float* __restrict__ gatew,
                                                  const float* __restrict__ gateb,
                                                  float* __restrict__ hn) {
  __shared__ __align__(16) char lds[49152 + 16384];
  bf16*  qkv_s = (bf16*)lds;           // [64][384]
  float* o2_s  = (float*)lds;          // [64][132] f32, aliases qkv_s (phase C+)
  char*  o_raw = lds + 49152;          // [64][256B] bf16, swizzled

  const int tid = threadIdx.x;
  const int b0 = blockIdx.x * 16;

  // ---- phase A: stage qkv ----
#pragma unroll
  for (int i = 0; i < 12; ++i) {
    const int idx = i * 256 + tid;     // 0..3071  (64 rows x 48 chunks)
    const int r = idx / 48, ch = idx - r * 48;
    const int c = r >> 4, bj = r & 15;
    bf16x8 v = load8(qkv + ((long)c * B_ + b0 + bj) * G3H + ch * 8);
    *(bf16x8*)(qkv_s + r * 384 + ch * 8) = v;
  }
  __syncthreads();

  // ---- phase B: attention ----
  {
    const int d = tid & 31;
    const int pair = tid >> 5;  // 0..7
#pragma unroll
    for (int pi = 0; pi < 8; ++pi) {
      const int idx = pi * 8 + pair;   // 0..63
      const int bj = idx >> 2, head = idx & 3;
      float q[C_], k[C_], v[C_];
#pragma unroll
      for (int c = 0; c < C_; ++c) {
        const bf16* row = qkv_s + (c * 16 + bj) * 384 + head * 32 + d;
        q[c] = bf2f(row[0]);
        k[c] = bf2f(row[128]);
        v[c] = bf2f(row[256]);
      }
      float a[C_][C_];
#pragma unroll
      for (int qc = 0; qc < C_; ++qc) {
#pragma unroll
        for (int kc = 0; kc < C_; ++kc) {
          float pdot = q[qc] * k[kc];
#pragma unroll
          for (int off = 16; off; off >>= 1) pdot += __shfl_xor(pdot, off, 32);
          a[qc][kc] = pdot * 0.17677669529663687f;  // 1/sqrt(32)
        }
      }
#pragma unroll
      for (int qc = 0; qc < C_; ++qc) {
        float m = fmaxf(fmaxf(a[qc][0], a[qc][1]), fmaxf(a[qc][2], a[qc][3]));
        float s = 0.f;
#pragma unroll
        for (int kc = 0; kc < C_; ++kc) {
          a[qc][kc] = __expf(a[qc][kc] - m);
          s += a[qc][kc];
        }
        float inv = 1.f / s;
        float ov = 0.f;
#pragma unroll
        for (int kc = 0; kc < C_; ++kc) ov += a[qc][kc] * v[kc];
        const int orow = qc * 16 + bj;
        const int boff = (orow * 256 + (head * 32 + d) * 2) ^ ((orow & 7) << 4);
        *(bf16*)(o_raw + boff) = f2bf(ov * inv);
      }
    }
  }
  __syncthreads();  // o_raw ready; qkv_s dead -> o2_s may alias

  // ---- phase C: oproj GEMM ----
  {
    const int wave = tid >> 6, lane = tid & 63;
    const int sub = lane & 15, quad = lane >> 4;
#pragma unroll
    for (int p = 0; p < 2; ++p) {
      const int col = wave * 32 + p * 16 + sub;
      bf16x8 wf[4];
      const bf16* Wp = w + (long)col * H_ + quad * 8;
#pragma unroll
      for (int kc = 0; kc < 4; ++kc) wf[kc] = load8(Wp + kc * 32);
      const float bv = bias[col];
#pragma unroll
      for (int rt = 0; rt < 4; ++rt) {
        bf16x8 af[4];
#pragma unroll
        for (int kc = 0; kc < 4; ++kc) {
          const int lrow = rt * 16 + sub;
          af[kc] = *(const bf16x8*)(o_raw +
                    ((lrow * 256 + kc * 64 + quad * 16) ^ ((lrow & 7) << 4)));
        }
        floatx4 acc = {0.f, 0.f, 0.f, 0.f};
#pragma unroll
        for (int kc = 0; kc < 4; ++kc) acc = mfma16(af[kc], wf[kc], acc);
#pragma unroll
        for (int r = 0; r < 4; ++r)
          o2_s[(rt * 16 + quad * 4 + r) * 132 + col] = acc[r] + bv;
      }
    }
  }
  __syncthreads();

  // ---- phase D: LN + gate + blend ----
  {
    const int wave = tid >> 6, lane = tid & 63;
#pragma unroll
    for (int rr = 0; rr < 16; ++rr) {
      const int row = wave * 16 + rr;
      const int j1 = lane, j2 = lane + 64;
      float v1 = o2_s[row * 132 + j1], v2 = o2_s[row * 132 + j2];
      float mu = wave_sum(v1 + v2) * (1.f / 128.f);
      float d1 = v1 - mu, d2 = v2 - mu;
      float var = wave_sum(d1 * d1 + d2 * d2) * (1.f / 128.f);
      float rs = rsqrtf(var + 1e-5f);
      float m1 = d1 * rs * g[j1] + bb[j1];
      float m2 = d2 * rs * g[j2] + bb[j2];
      const int qc = row >> 4, bj = row & 15;
      const long grow = (long)qc * B_ + b0 + bj;
      float h1 = hn[grow * H_ + j1], h2 = hn[grow * H_ + j2];
      float gp = h1 * gatew[j1] + m1 * gatew[128 + j1] +
                 h2 * gatew[j2] + m2 * gatew[128 + j2];
      float gt = 1.f / (1.f + __expf(-(wave_sum(gp) + gateb[0])));
      hn[grow * H_ + j1] = (1.f - gt) * h1 + gt * m1;
      hn[grow * H_ + j2] = (1.f - gt) * h2 + gt * m2;
    }
  }
}

extern "C" void kernel_launch(void* const* d_in, const int* in_sizes, int n_in,
                              void* d_out, int out_size, void* d_ws, size_t ws_size,
                              hipStream_t stream) {
  const int*   tokens = (const int*)d_in[0];
  const float* h      = (const float*)d_in[1];
  const float* emb    = (const float*)d_in[2];
  const float* wih0c0 = (const float*)d_in[3];
  const float* bih0   = (const float*)d_in[5];
  const float* whh0   = (const float*)d_in[6];
  const float* bhh0   = (const float*)d_in[7];
  const float* wih    = (const float*)d_in[8];
  const float* whh    = (const float*)d_in[9];
  const float* bih    = (const float*)d_in[10];
  const float* bhh    = (const float*)d_in[11];
  const float* ainw   = (const float*)d_in[12];
  const float* ainb   = (const float*)d_in[13];
  const float* aoutw  = (const float*)d_in[14];
  const float* aoutb  = (const float*)d_in[15];
  const float* lng    = (const float*)d_in[16];
  const float* lnb    = (const float*)d_in[17];
  const float* gw     = (const float*)d_in[18];
  const float* gb     = (const float*)d_in[19];
  const float* headw  = (const float*)d_in[20];
  const float* headb  = (const float*)d_in[21];

  float* y_out  = (float*)d_out;                 // (B, O)
  float* hn_out = (float*)d_out + (long)B_ * O_; // (L, C, B, H)

  // workspace layout (bf16 elements)
  bf16* ws = (bf16*)d_ws;
  bf16* bufA = ws;                          // qkv: CB*384 = 48 MiB
  bf16* x0   = bufA + (long)CB * G3H;       // B*128
  bf16* wp   = x0 + (long)CB * H_;          // (slot kept CB*128 wide)
  bf16* wih0bf  = wp;                  wp += 49152;   // 384*128
  bf16* whh0bf  = wp;                  wp += 196608;  // 4*384*128
  bf16* wihbf   = wp;                  wp += 983040;  // 5*4*384*128
  bf16* whhbf   = wp;                  wp += 983040;
  bf16* ainwbf  = wp;                  wp += 294912;  // 6*384*128
  bf16* aoutwbf = wp;                  wp += 98304;   // 6*128*128
  bf16* headwbf = wp;                  wp += 131072;  // 1024*128

  dim3 blk(256);

  // single-launch weight conversion (dst segments are contiguous from wih0bf)
  {
    Cvt7 a;
    const float* srcs[7] = {wih0c0, whh0, wih, whh, ainw, aoutw, headw};
    const long lens[7] = {49152, 196608, 983040, 983040, 294912, 98304, 131072};
    long cum = 0;
    for (int i = 0; i < 7; ++i) { a.src[i] = srcs[i]; a.start4[i] = cum / 4; cum += lens[i]; }
    a.start4[7] = cum / 4;
    const long n4 = cum / 4;  // 684032
    cvt7_kernel<<<(int)((n4 + 255) / 256), blk, 0, stream>>>(a, wih0bf);
  }

  embed_kernel<<<B_, 128, 0, stream>>>(tokens, emb, x0);

  for (int l = 0; l < L_; ++l) {
    float* hn_l = hn_out + (long)l * CBH;
    const float* hl = h + (long)l * CBH;

    // fused gi+gh+GRU+qkv -> hn_l (f32) + bufA (qkv bf16)
    if (l == 0) {
      cell_fused<true><<<CB / 64, blk, 0, stream>>>(
          nullptr, x0, wih0bf, bih0, hl, whh0bf, bhh0,
          ainwbf, ainb, hn_l, bufA);
    } else {
      cell_fused<false><<<CB / 64, blk, 0, stream>>>(
          hn_out + (long)(l - 1) * CBH, nullptr,
          wihbf + (long)(l - 1) * C_ * G3H * H_, bih + (long)(l - 1) * C_ * G3H,
          hl, whhbf + (long)(l - 1) * C_ * G3H * H_, bhh + (long)(l - 1) * C_ * G3H,
          ainwbf + (long)l * G3H * H_, ainb + (long)l * G3H, hn_l, bufA);
    }

    // fused attention + out-proj + LN + gate + blend -> hn_l (final, f32)
    attn_oproj<<<B_ / 16, blk, 0, stream>>>(
        bufA, aoutwbf + (long)l * H_ * H_, aoutb + (long)l * H_,
        lng + l * H_, lnb + l * H_, gw + l * 2 * H_, gb + l, hn_l);
  }

  // head: y = h_n[5, c=0] @ head_w^T + head_b
  gemm_bt<float, float><<<dim3(B_ / 16, O_ / 64), blk, 0, stream>>>(
      hn_out + (long)5 * CBH, headwbf, headb, y_out, O_, B_, 0, 0);
}

// Round 4
// 1073.683 us; speedup vs baseline: 1.6678x; 1.1995x over previous
//
#include <hip/hip_runtime.h>
#include <hip/hip_bf16.h>

// ---- problem constants ----
#define B_   16384
#define H_   128
#define C_   4
#define L_   6
#define O_   1024
#define G3H  384
#define CB   (C_ * B_)
#define CBH  (C_ * B_ * H_)

typedef __hip_bfloat16 bf16;
using bf16x8  = __attribute__((ext_vector_type(8))) __bf16;
using bf16x4  = __attribute__((ext_vector_type(4))) __bf16;
using floatx4 = __attribute__((ext_vector_type(4))) float;

__device__ __forceinline__ bf16 f2bf(float x) { return __float2bfloat16(x); }
__device__ __forceinline__ float bf2f(bf16 x) { return __bfloat162float(x); }

__device__ __forceinline__ floatx4 mfma16(bf16x8 a, bf16x8 b, floatx4 c) {
  return __builtin_amdgcn_mfma_f32_16x16x32_bf16(a, b, c, 0, 0, 0);
}

// fragment loaders: 8 consecutive K elements
__device__ __forceinline__ bf16x8 load8(const bf16* p) { return *(const bf16x8*)p; }
__device__ __forceinline__ bf16x8 load8(const float* p) {
  const float4 a = *(const float4*)p;
  const float4 b = *(const float4*)(p + 4);
  bf16x8 r;
  r[0] = (__bf16)a.x; r[1] = (__bf16)a.y; r[2] = (__bf16)a.z; r[3] = (__bf16)a.w;
  r[4] = (__bf16)b.x; r[5] = (__bf16)b.y; r[6] = (__bf16)b.z; r[7] = (__bf16)b.w;
  return r;
}

__device__ __forceinline__ float sigmoidf_(float x) {
  return 1.f / (1.f + __expf(-x));
}
__device__ __forceinline__ float tanhf_(float x) {
  float e = __expf(2.f * x);
  return 1.f - 2.f / (e + 1.f);
}

// single-launch weight conversion: 7 contiguous dst segments (4-elem units)
struct Cvt7 {
  const float* src[7];
  long start4[8];  // cumulative lengths / 4
};
__global__ __launch_bounds__(256) void cvt7_kernel(Cvt7 a, bf16* __restrict__ dst) {
  long i4 = (long)blockIdx.x * 256 + threadIdx.x;
  if (i4 >= a.start4[7]) return;
  int s = 0;
#pragma unroll
  for (int k = 1; k < 7; ++k)
    if (i4 >= a.start4[k]) s = k;
  const float4 v = ((const float4*)a.src[s])[i4 - a.start4[s]];
  bf16x4 o;
  o[0] = (__bf16)v.x; o[1] = (__bf16)v.y; o[2] = (__bf16)v.z; o[3] = (__bf16)v.w;
  ((bf16x4*)dst)[i4] = o;
}

// ---------------------------------------------------------------------------
// Fused per-cell kernel, v4: 64-row blocks, LDS-staged activations.
//  S) stage h (and x / emb[tok]) f32->bf16 into XOR-swizzled LDS.
//  1) GEMM1 (gi+gh): wave w cols [32w,32w+32); 24 weight frags/pass in regs,
//     reused over 4 row-tiles from LDS.  r,z co-accumulate gi+gh.
//  2) GRU in registers -> hn f32 global + bf16 swizzled LDS tile.
//  3) qkv GEMM: hn A-frags hoisted to regs; results go to a swizzled LDS
//     tile (aliases staging bufs) then one coalesced dwordx4 copy-out.
// ---------------------------------------------------------------------------
template <bool L0>
__global__ __launch_bounds__(256) void cell_fused(const float* __restrict__ x,
                                                  const int* __restrict__ tok,
                                                  const float* __restrict__ emb,
                                                  const bf16* __restrict__ wih_l,
                                                  const float* __restrict__ bih_l,
                                                  const float* __restrict__ h,
                                                  const bf16* __restrict__ whh_l,
                                                  const float* __restrict__ bhh_l,
                                                  const bf16* __restrict__ ainw,
                                                  const float* __restrict__ ainb,
                                                  float* __restrict__ hn,
                                                  bf16* __restrict__ qkv) {
  __shared__ __align__(16) char lds[3 * 16384];
  char* h_raw  = lds;             // 64 x 256B bf16, swizzled
  char* x_raw  = lds + 16384;
  char* hn_raw = lds + 32768;
  char* qkv_raw = lds;            // 64 x 768B, aliases everything in phase 3

  const int tid = threadIdx.x;
  const int wave = tid >> 6, lane = tid & 63;
  const int sub = lane & 15, quad = lane >> 4;
  const int m0 = blockIdx.x * 64;
  const int cell = m0 / B_;
  const bool has_gi = (!L0) || (cell == 0);

  // ---- phase S: stage activations ----
  {
    const int colg = tid & 15;   // 8-col group
    const int rb   = tid >> 4;   // 0..15
#pragma unroll
    for (int i = 0; i < 4; ++i) {
      const int row = i * 16 + rb;
      bf16x8 v = load8(h + (long)(m0 + row) * H_ + colg * 8);
      *(bf16x8*)(h_raw + ((row * 256 + colg * 16) ^ ((row & 7) << 4))) = v;
    }
    if (has_gi) {
      if constexpr (L0) {
#pragma unroll
        for (int i = 0; i < 4; ++i) {
          const int row = i * 16 + rb;
          const int tk = tok[m0 + row];
          bf16x8 v = load8(emb + (long)tk * 128 + colg * 8);
          *(bf16x8*)(x_raw + ((row * 256 + colg * 16) ^ ((row & 7) << 4))) = v;
        }
      } else {
#pragma unroll
        for (int i = 0; i < 4; ++i) {
          const int row = i * 16 + rb;
          bf16x8 v = load8(x + (long)(m0 + row) * H_ + colg * 8);
          *(bf16x8*)(x_raw + ((row * 256 + colg * 16) ^ ((row & 7) << 4))) = v;
        }
      }
    }
  }
  __syncthreads();

  const bf16*  Wh = whh_l + (long)cell * G3H * H_;
  const bf16*  Wi = L0 ? wih_l : wih_l + (long)cell * G3H * H_;
  const float* bh = bhh_l + cell * G3H;
  const float* bi = bih_l + cell * G3H;

  // ---- phases 1+2: GEMM1 + GRU ----
#pragma unroll
  for (int p = 0; p < 2; ++p) {
    const int colr = wave * 32 + p * 16 + sub;  // output col in [0,128)

    bf16x8 wfr[3][4], wif[3][4];
#pragma unroll
    for (int g = 0; g < 3; ++g) {
      const bf16* Wg = Wh + (long)(g * 128 + colr) * H_ + quad * 8;
#pragma unroll
      for (int kc = 0; kc < 4; ++kc) wfr[g][kc] = load8(Wg + kc * 32);
    }
    if (has_gi) {
#pragma unroll
      for (int g = 0; g < 3; ++g) {
        const bf16* Wg = Wi + (long)(g * 128 + colr) * H_ + quad * 8;
#pragma unroll
        for (int kc = 0; kc < 4; ++kc) wif[g][kc] = load8(Wg + kc * 32);
      }
    }

    const float bir = bi[colr],        bhr = bh[colr];
    const float biz = bi[128 + colr],  bhz = bh[128 + colr];
    const float bin_ = bi[256 + colr], bhn = bh[256 + colr];

#pragma unroll
    for (int rt = 0; rt < 4; ++rt) {
      bf16x8 hfr[4];
#pragma unroll
      for (int kc = 0; kc < 4; ++kc) {
        const int lrow = rt * 16 + sub;
        hfr[kc] = *(const bf16x8*)(h_raw +
                   ((lrow * 256 + kc * 64 + quad * 16) ^ ((lrow & 7) << 4)));
      }
      floatx4 ar = {0.f, 0.f, 0.f, 0.f}, az = {0.f, 0.f, 0.f, 0.f};
      floatx4 anh = {0.f, 0.f, 0.f, 0.f}, ani = {0.f, 0.f, 0.f, 0.f};
#pragma unroll
      for (int kc = 0; kc < 4; ++kc) {
        ar  = mfma16(hfr[kc], wfr[0][kc], ar);
        az  = mfma16(hfr[kc], wfr[1][kc], az);
        anh = mfma16(hfr[kc], wfr[2][kc], anh);
      }
      if (has_gi) {
        bf16x8 xfr[4];
#pragma unroll
        for (int kc = 0; kc < 4; ++kc) {
          const int lrow = rt * 16 + sub;
          xfr[kc] = *(const bf16x8*)(x_raw +
                     ((lrow * 256 + kc * 64 + quad * 16) ^ ((lrow & 7) << 4)));
        }
#pragma unroll
        for (int kc = 0; kc < 4; ++kc) {
          ar  = mfma16(xfr[kc], wif[0][kc], ar);   // r: gi+gh co-accumulated
          az  = mfma16(xfr[kc], wif[1][kc], az);   // z: gi+gh co-accumulated
          ani = mfma16(xfr[kc], wif[2][kc], ani);  // n: kept separate
        }
      }

      // GRU elementwise (C/D layout: row = rt*16 + quad*4 + r, col = colr)
#pragma unroll
      for (int r = 0; r < 4; ++r) {
        const int lrow = rt * 16 + quad * 4 + r;
        const long grow = m0 + lrow;
        float rg = sigmoidf_(ar[r] + bir + bhr);
        float zg = sigmoidf_(az[r] + biz + bhz);
        float ng = tanhf_(ani[r] + bin_ + rg * (anh[r] + bhn));
        float hv = h[grow * H_ + colr];
        float hnv = (1.f - zg) * ng + zg * hv;
        hn[grow * H_ + colr] = hnv;
        *(bf16*)(hn_raw + ((lrow * 256 + colr * 2) ^ ((lrow & 7) << 4))) = f2bf(hnv);
      }
    }
  }
  __syncthreads();

  // ---- phase 3: qkv GEMM, A-frags hoisted, LDS repack, coalesced store ----
  bf16x8 af[4][4];
#pragma unroll
  for (int rt = 0; rt < 4; ++rt) {
#pragma unroll
    for (int kc = 0; kc < 4; ++kc) {
      const int lrow = rt * 16 + sub;
      af[rt][kc] = *(const bf16x8*)(hn_raw +
                    ((lrow * 256 + kc * 64 + quad * 16) ^ ((lrow & 7) << 4)));
    }
  }
  __syncthreads();  // all hn_raw reads done; lds becomes qkv_raw

#pragma unroll
  for (int t = 0; t < 6; ++t) {
    const int col = wave * 96 + t * 16 + sub;
    bf16x8 wf[4];
    const bf16* Wp = ainw + (long)col * H_ + quad * 8;
#pragma unroll
    for (int kc = 0; kc < 4; ++kc) wf[kc] = load8(Wp + kc * 32);
    const float bv = ainb[col];
#pragma unroll
    for (int rt = 0; rt < 4; ++rt) {
      floatx4 acc = {0.f, 0.f, 0.f, 0.f};
#pragma unroll
      for (int kc = 0; kc < 4; ++kc) acc = mfma16(af[rt][kc], wf[kc], acc);
#pragma unroll
      for (int r = 0; r < 4; ++r) {
        const int lrow = rt * 16 + quad * 4 + r;
        // swizzle: XOR bits 5-6 with (lrow>>2)&3 -> per-quad distinct banks
        *(bf16*)(qkv_raw + ((lrow * 768 + col * 2) ^ ((lrow & 12) << 3))) =
            f2bf(acc[r] + bv);
      }
    }
  }
  __syncthreads();

  // coalesced copy-out: 64 rows x 48 chunks of 16B
#pragma unroll
  for (int i = 0; i < 12; ++i) {
    const int m = i * 256 + tid;
    const int row = m / 48, ch = m - row * 48;
    bf16x8 v = *(const bf16x8*)(qkv_raw + ((row * 768 + ch * 16) ^ ((row & 12) << 3)));
    *(bf16x8*)(qkv + (long)(m0 + row) * G3H + ch * 8) = v;
  }
}

// ---------------------------------------------------------------------------
// Fused attention + out-proj + LN + gate + blend, v2 (MFMA QK^T).
// Block = 16 batch elems x 4 cells = 64 o-rows, 256 threads.
//  A) stage qkv tile to LDS (stride 392 elems), stage g/bb/gatew to LDS.
//  B) QK^T via mfma16: per (head=wave, b-group bg): rows=(bi,qc), cols=(bj,kc),
//     K=d32.  Block-diag lanes (quad==sub>>2) hold b's 4x4 scores; softmax =
//     4 shfl; normalized probs -> p_s[16][4][4][4].
//  PV) per-thread 4 chunks of 8 d's: o = sum_kc p*v; write swizzled o_raw.
//  C) oproj GEMM (A-frags hoisted), o2 -> LDS f32 (aliases qkv_s).
//  D) LN + gate + blend: 4 threads/row x 32 cols; 6 shfl/thread.
// ---------------------------------------------------------------------------
__global__ __launch_bounds__(256) void attn_oproj(const bf16* __restrict__ qkv,
                                                  const bf16* __restrict__ w,
                                                  const float* __restrict__ bias,
                                                  const float* __restrict__ g,
                                                  const float* __restrict__ bb,
                                                  const float* __restrict__ gatew,
                                                  const float* __restrict__ gateb,
                                                  float* __restrict__ hn) {
  // qkv_s 64x784B = 50176 | p_s 4096 | o_raw 16384 | params 2048
  __shared__ __align__(16) char lds[50176 + 4096 + 16384 + 2048];
  char*  qbase = lds;
  float* p_s   = (float*)(lds + 50176);          // [16 b][4 hd][4 qc][4 kc]
  char*  o_raw = lds + 50176 + 4096;             // [64][256B] swizzled
  float* prm   = (float*)(lds + 50176 + 4096 + 16384);  // g[128] bb[128] gw[256]
  float* o2_s  = (float*)lds;                    // [64][132] f32, aliases qkv_s

  const int tid = threadIdx.x;
  const int wave = tid >> 6, lane = tid & 63;
  const int sub = lane & 15, quad = lane >> 4;
  const int b0 = blockIdx.x * 16;

  // ---- phase A: stage qkv (+ params) ----
#pragma unroll
  for (int i = 0; i < 12; ++i) {
    const int idx = i * 256 + tid;     // 64 rows x 48 chunks
    const int r = idx / 48, ch = idx - r * 48;
    const int c = r >> 4, bj = r & 15;
    bf16x8 v = load8(qkv + ((long)c * B_ + b0 + bj) * G3H + ch * 8);
    *(bf16x8*)(qbase + r * 784 + ch * 16) = v;
  }
  if (tid < 128) {
    prm[tid] = g[tid];
    prm[128 + tid] = bb[tid];
    prm[256 + tid] = gatew[tid];
    prm[384 + tid] = gatew[128 + tid];
  }
  __syncthreads();

  // ---- phase B: QK^T (MFMA) + softmax ----
  {
    const int hd = wave;
    const int bi = sub >> 2, qc = sub & 3;   // A-row decomposition
    const int bjx = sub >> 2, kc = sub & 3;  // B-col decomposition
#pragma unroll
    for (int bg = 0; bg < 4; ++bg) {
      const int rq = qc * 16 + bg * 4 + bi;   // Q source row
      const int rk = kc * 16 + bg * 4 + bjx;  // K source row
      bf16x8 qa = *(const bf16x8*)(qbase + rq * 784 + hd * 64 + quad * 16);
      bf16x8 kb = *(const bf16x8*)(qbase + rk * 784 + 256 + hd * 64 + quad * 16);
      floatx4 sc = {0.f, 0.f, 0.f, 0.f};
      sc = mfma16(qa, kb, sc);
      // lanes with quad == bjx hold scores[qc=r][kc] for b-local = bg*4+quad
      float p[4];
#pragma unroll
      for (int r = 0; r < 4; ++r) {
        float s = sc[r] * 0.17677669529663687f;  // 1/sqrt(32)
        float m = fmaxf(s, __shfl_xor(s, 1));
        m = fmaxf(m, __shfl_xor(m, 2));
        float e = __expf(s - m);
        float ssum = e + __shfl_xor(e, 1);
        ssum += __shfl_xor(ssum, 2);
        p[r] = e / ssum;
      }
      if (quad == bjx) {
        const int bl = bg * 4 + quad;
#pragma unroll
        for (int r = 0; r < 4; ++r)
          p_s[((bl * 4 + hd) * 4 + r) * 4 + kc] = p[r];
      }
    }
  }
  __syncthreads();

  // ---- phase PV ----
#pragma unroll
  for (int i = 0; i < 4; ++i) {
    const int m = i * 256 + tid;       // 0..1023
    const int row = m >> 4;            // 0..63 = qc*16 + bj
    const int ch = m & 15;             // 8-d chunk; head = ch>>2
    const int qc = row >> 4, bj = row & 15;
    const int hd = ch >> 2;
    float acc[8];
#pragma unroll
    for (int j = 0; j < 8; ++j) acc[j] = 0.f;
#pragma unroll
    for (int kc = 0; kc < 4; ++kc) {
      const float pv = p_s[((bj * 4 + hd) * 4 + qc) * 4 + kc];
      bf16x8 vv = *(const bf16x8*)(qbase + (kc * 16 + bj) * 784 + 512 + ch * 16);
#pragma unroll
      for (int j = 0; j < 8; ++j) acc[j] += pv * (float)vv[j];
    }
    bf16x8 ov;
#pragma unroll
    for (int j = 0; j < 8; ++j) ov[j] = (__bf16)acc[j];
    *(bf16x8*)(o_raw + ((row * 256 + ch * 16) ^ ((row & 7) << 4))) = ov;
  }
  __syncthreads();  // o_raw ready; qkv_s dead -> o2_s may alias

  // ---- phase C: oproj GEMM (A-frags hoisted) ----
  {
    bf16x8 af[4][4];
#pragma unroll
    for (int rt = 0; rt < 4; ++rt) {
#pragma unroll
      for (int kc = 0; kc < 4; ++kc) {
        const int lrow = rt * 16 + sub;
        af[rt][kc] = *(const bf16x8*)(o_raw +
                      ((lrow * 256 + kc * 64 + quad * 16) ^ ((lrow & 7) << 4)));
      }
    }
#pragma unroll
    for (int p = 0; p < 2; ++p) {
      const int col = wave * 32 + p * 16 + sub;
      bf16x8 wf[4];
      const bf16* Wp = w + (long)col * H_ + quad * 8;
#pragma unroll
      for (int kc = 0; kc < 4; ++kc) wf[kc] = load8(Wp + kc * 32);
      const float bv = bias[col];
#pragma unroll
      for (int rt = 0; rt < 4; ++rt) {
        floatx4 acc = {0.f, 0.f, 0.f, 0.f};
#pragma unroll
        for (int kc = 0; kc < 4; ++kc) acc = mfma16(af[rt][kc], wf[kc], acc);
#pragma unroll
        for (int r = 0; r < 4; ++r)
          o2_s[(rt * 16 + quad * 4 + r) * 132 + col] = acc[r] + bv;
      }
    }
  }
  __syncthreads();

  // ---- phase D: LN + gate + blend (4 threads per row, 32 cols each) ----
  {
    const int row = tid >> 2;          // 0..63
    const int c0 = (tid & 3) * 32;
    float s = 0.f;
#pragma unroll
    for (int j = 0; j < 32; j += 4) {
      float4 v = *(const float4*)&o2_s[row * 132 + c0 + j];
      s += v.x + v.y + v.z + v.w;
    }
    s += __shfl_xor(s, 1);
    s += __shfl_xor(s, 2);
    const float mu = s * (1.f / 128.f);
    float vs = 0.f;
#pragma unroll
    for (int j = 0; j < 32; j += 4) {
      float4 v = *(const float4*)&o2_s[row * 132 + c0 + j];
      float d0 = v.x - mu, d1 = v.y - mu, d2 = v.z - mu, d3 = v.w - mu;
      vs += d0 * d0 + d1 * d1 + d2 * d2 + d3 * d3;
    }
    vs += __shfl_xor(vs, 1);
    vs += __shfl_xor(vs, 2);
    const float rs = rsqrtf(vs * (1.f / 128.f) + 1e-5f);

    const int qc = row >> 4, bj = row & 15;
    const long grow = (long)qc * B_ + b0 + bj;
    float mv[32], hv[32];
    float gp = 0.f;
#pragma unroll
    for (int j = 0; j < 32; j += 4) {
      float4 v = *(const float4*)&o2_s[row * 132 + c0 + j];
      float4 hh = *(const float4*)&hn[grow * H_ + c0 + j];
      float vv[4] = {v.x, v.y, v.z, v.w};
      float hh4[4] = {hh.x, hh.y, hh.z, hh.w};
#pragma unroll
      for (int q = 0; q < 4; ++q) {
        const int c = c0 + j + q;
        float mval = (vv[q] - mu) * rs * prm[c] + prm[128 + c];
        mv[j + q] = mval;
        hv[j + q] = hh4[q];
        gp += hh4[q] * prm[256 + c] + mval * prm[384 + c];
      }
    }
    gp += __shfl_xor(gp, 1);
    gp += __shfl_xor(gp, 2);
    const float gt = 1.f / (1.f + __expf(-(gp + gateb[0])));
#pragma unroll
    for (int j = 0; j < 32; j += 4) {
      float4 o;
      o.x = (1.f - gt) * hv[j]     + gt * mv[j];
      o.y = (1.f - gt) * hv[j + 1] + gt * mv[j + 1];
      o.z = (1.f - gt) * hv[j + 2] + gt * mv[j + 2];
      o.w = (1.f - gt) * hv[j + 3] + gt * mv[j + 3];
      *(float4*)&hn[grow * H_ + c0 + j] = o;
    }
  }
}

// ---------------------------------------------------------------------------
// Head GEMM: y = A @ W^T + b.  Block = 64 rows x 256 cols, A staged in LDS.
// ---------------------------------------------------------------------------
__global__ __launch_bounds__(256) void head_gemm(const float* __restrict__ A,
                                                 const bf16* __restrict__ W,
                                                 const float* __restrict__ bias,
                                                 float* __restrict__ out) {
  __shared__ __align__(16) char a_raw[64 * 256];
  const int tid = threadIdx.x;
  const int wave = tid >> 6, lane = tid & 63;
  const int sub = lane & 15, quad = lane >> 4;
  const int m0 = blockIdx.x * 64;
  const int nb = blockIdx.y * 256;

  {
    const int colg = tid & 15;
    const int rb = tid >> 4;
#pragma unroll
    for (int i = 0; i < 4; ++i) {
      const int row = i * 16 + rb;
      bf16x8 v = load8(A + (long)(m0 + row) * H_ + colg * 8);
      *(bf16x8*)(a_raw + ((row * 256 + colg * 16) ^ ((row & 7) << 4))) = v;
    }
  }
  __syncthreads();

  bf16x8 af[4][4];
#pragma unroll
  for (int rt = 0; rt < 4; ++rt) {
#pragma unroll
    for (int kc = 0; kc < 4; ++kc) {
      const int lrow = rt * 16 + sub;
      af[rt][kc] = *(const bf16x8*)(a_raw +
                    ((lrow * 256 + kc * 64 + quad * 16) ^ ((lrow & 7) << 4)));
    }
  }
#pragma unroll
  for (int ct = 0; ct < 4; ++ct) {
    const int col = nb + wave * 64 + ct * 16 + sub;
    bf16x8 wf[4];
    const bf16* Wp = W + (long)col * H_ + quad * 8;
#pragma unroll
    for (int kc = 0; kc < 4; ++kc) wf[kc] = load8(Wp + kc * 32);
    const float bv = bias[col];
#pragma unroll
    for (int rt = 0; rt < 4; ++rt) {
      floatx4 acc = {0.f, 0.f, 0.f, 0.f};
#pragma unroll
      for (int kc = 0; kc < 4; ++kc) acc = mfma16(af[rt][kc], wf[kc], acc);
#pragma unroll
      for (int r = 0; r < 4; ++r)
        out[(long)(m0 + rt * 16 + quad * 4 + r) * O_ + col] = acc[r] + bv;
    }
  }
}

extern "C" void kernel_launch(void* const* d_in, const int* in_sizes, int n_in,
                              void* d_out, int out_size, void* d_ws, size_t ws_size,
                              hipStream_t stream) {
  const int*   tokens = (const int*)d_in[0];
  const float* h      = (const float*)d_in[1];
  const float* emb    = (const float*)d_in[2];
  const float* wih0c0 = (const float*)d_in[3];
  const float* bih0   = (const float*)d_in[5];
  const float* whh0   = (const float*)d_in[6];
  const float* bhh0   = (const float*)d_in[7];
  const float* wih    = (const float*)d_in[8];
  const float* whh    = (const float*)d_in[9];
  const float* bih    = (const float*)d_in[10];
  const float* bhh    = (const float*)d_in[11];
  const float* ainw   = (const float*)d_in[12];
  const float* ainb   = (const float*)d_in[13];
  const float* aoutw  = (const float*)d_in[14];
  const float* aoutb  = (const float*)d_in[15];
  const float* lng    = (const float*)d_in[16];
  const float* lnb    = (const float*)d_in[17];
  const float* gw     = (const float*)d_in[18];
  const float* gb     = (const float*)d_in[19];
  const float* headw  = (const float*)d_in[20];
  const float* headb  = (const float*)d_in[21];

  float* y_out  = (float*)d_out;                 // (B, O)
  float* hn_out = (float*)d_out + (long)B_ * O_; // (L, C, B, H)

  // workspace layout (bf16 elements)
  bf16* ws = (bf16*)d_ws;
  bf16* bufA = ws;                          // qkv: CB*384 = 48 MiB
  bf16* wp   = bufA + (long)CB * G3H;
  bf16* wih0bf  = wp;                  wp += 49152;   // 384*128
  bf16* whh0bf  = wp;                  wp += 196608;  // 4*384*128
  bf16* wihbf   = wp;                  wp += 983040;  // 5*4*384*128
  bf16* whhbf   = wp;                  wp += 983040;
  bf16* ainwbf  = wp;                  wp += 294912;  // 6*384*128
  bf16* aoutwbf = wp;                  wp += 98304;   // 6*128*128
  bf16* headwbf = wp;                  wp += 131072;  // 1024*128

  dim3 blk(256);

  // single-launch weight conversion (dst segments contiguous from wih0bf)
  {
    Cvt7 a;
    const float* srcs[7] = {wih0c0, whh0, wih, whh, ainw, aoutw, headw};
    const long lens[7] = {49152, 196608, 983040, 983040, 294912, 98304, 131072};
    long cum = 0;
    for (int i = 0; i < 7; ++i) { a.src[i] = srcs[i]; a.start4[i] = cum / 4; cum += lens[i]; }
    a.start4[7] = cum / 4;
    const long n4 = cum / 4;
    cvt7_kernel<<<(int)((n4 + 255) / 256), blk, 0, stream>>>(a, wih0bf);
  }

  for (int l = 0; l < L_; ++l) {
    float* hn_l = hn_out + (long)l * CBH;
    const float* hl = h + (long)l * CBH;

    if (l == 0) {
      cell_fused<true><<<CB / 64, blk, 0, stream>>>(
          nullptr, tokens, emb, wih0bf, bih0, hl, whh0bf, bhh0,
          ainwbf, ainb, hn_l, bufA);
    } else {
      cell_fused<false><<<CB / 64, blk, 0, stream>>>(
          hn_out + (long)(l - 1) * CBH, nullptr, nullptr,
          wihbf + (long)(l - 1) * C_ * G3H * H_, bih + (long)(l - 1) * C_ * G3H,
          hl, whhbf + (long)(l - 1) * C_ * G3H * H_, bhh + (long)(l - 1) * C_ * G3H,
          ainwbf + (long)l * G3H * H_, ainb + (long)l * G3H, hn_l, bufA);
    }

    attn_oproj<<<B_ / 16, blk, 0, stream>>>(
        bufA, aoutwbf + (long)l * H_ * H_, aoutb + (long)l * H_,
        lng + l * H_, lnb + l * H_, gw + l * 2 * H_, gb + l, hn_l);
  }

  // head: y = h_n[5, c=0] @ head_w^T + head_b
  head_gemm<<<dim3(B_ / 64, O_ / 256), blk, 0, stream>>>(
      hn_out + (long)5 * CBH, headwbf, headb, y_out);
}